// Round 2
// baseline (204.802 us; speedup 1.0000x reference)
//
#include <hip/hip_runtime.h>
#include <hip/hip_cooperative_groups.h>
#include <math.h>

namespace cg = cooperative_groups;

struct Params {
    const float* logits;
    const int* labels;
    const float* x;
    const int* row;
    const int* col;
    const int* batch;
    unsigned int* deg;
    double* energy_acc;
    double* ce_acc;
    unsigned int* hitCount;
    int2* hits;
    float* out;
    int G, C, E, N, D;
};

__global__ __launch_bounds__(256, 4) void fused_gcod(Params p) {
    cg::grid_group grid = cg::this_grid();
    const int tid = blockIdx.x * blockDim.x + threadIdx.x;
    const int nthreads = gridDim.x * blockDim.x;

    // ---------------- phase 0: zero deg + accumulators; block 0 does CE ----
    for (int i = tid; i < p.N; i += nthreads) p.deg[i] = 0u;
    if (tid == 0) { *p.energy_acc = 0.0; *p.hitCount = 0u; }

    __shared__ float sh[128];
    if (blockIdx.x == 0) {
        int g = threadIdx.x;
        float lp = 0.f;
        if (g < p.G) {
            const float* lg = p.logits + (size_t)g * p.C;
            float m = lg[0];
            for (int d = 1; d < p.C; ++d) m = fmaxf(m, lg[d]);
            float s = 0.f;
            for (int d = 0; d < p.C; ++d) s += expf(lg[d] - m);
            lp = lg[p.labels[g]] - m - logf(s);
        }
        if (threadIdx.x < 128) sh[threadIdx.x] = lp;
        __syncthreads();
        for (int o = 64; o > 0; o >>= 1) {
            if (threadIdx.x < o) sh[threadIdx.x] += sh[threadIdx.x + o];
            __syncthreads();
        }
        if (threadIdx.x == 0) *p.ce_acc = -(double)sh[0] / (double)p.G;
    }
    grid.sync();

    // ---------------- phase 1: degree atomics + hit compaction -------------
    for (int e = tid; e < p.E; e += nthreads) {
        int r = p.row[e], c = p.col[e];
        if (p.batch[r] == p.batch[c]) {
            atomicAdd(&p.deg[r], 1u);
            unsigned int idx = atomicAdd(p.hitCount, 1u);
            p.hits[idx] = make_int2(r, c);
        }
    }
    grid.sync();

    // ---------------- phase 2: energy over compacted hits ------------------
    const int lane = threadIdx.x & 63;
    const int wave = tid >> 6;
    const int nwaves = nthreads >> 6;
    const int nH = (int)(*p.hitCount);

    double wsum = 0.0;
    for (int h = wave; h < nH; h += nwaves) {
        int2 rc = p.hits[h];
        unsigned int dr = p.deg[rc.x];
        unsigned int dc = p.deg[rc.y];
        if (dc == 0u) continue;  // dr >= 1 guaranteed (this edge counted into deg[r])
        const float4 a = ((const float4*)(p.x + (size_t)rc.x * (size_t)p.D))[lane];
        const float4 b = ((const float4*)(p.x + (size_t)rc.y * (size_t)p.D))[lane];
        float dx = a.x - b.x, dy = a.y - b.y, dz = a.z - b.z, dw = a.w - b.w;
        float ss = dx * dx + dy * dy + dz * dz + dw * dw;
        #pragma unroll
        for (int o = 32; o > 0; o >>= 1) ss += __shfl_xor(ss, o);
        if (lane == 0) {
            float ir = 1.0f / sqrtf((float)dr);
            float ic = 1.0f / sqrtf((float)dc);
            wsum += (double)((ir * ic) * ss);
        }
    }
    if (lane == 0 && wsum != 0.0) atomicAdd(p.energy_acc, wsum);
    grid.sync();

    // ---------------- phase 3: finalize ------------------------------------
    if (tid == 0) {
        double ng = (double)(p.batch[p.N - 1] + 1);
        p.out[0] = (float)(*p.ce_acc + *p.energy_acc / ng);
    }
}

extern "C" void kernel_launch(void* const* d_in, const int* in_sizes, int n_in,
                              void* d_out, int out_size, void* d_ws, size_t ws_size,
                              hipStream_t stream) {
    Params p;
    p.logits = (const float*)d_in[0];
    p.labels = (const int*)d_in[1];
    p.x      = (const float*)d_in[2];
    const int* edge_index = (const int*)d_in[3];
    p.batch  = (const int*)d_in[4];

    p.C = 10;
    p.G = in_sizes[0] / p.C;        // 128
    p.E = in_sizes[3] / 2;          // 320000
    p.N = in_sizes[4];              // 100000
    p.D = in_sizes[2] / p.N;        // 256

    p.row = edge_index;
    p.col = edge_index + p.E;

    // workspace layout: deg[N] | energy_acc | ce_acc | hitCount | pad | hits[E]
    size_t off = 0;
    p.deg = (unsigned int*)((char*)d_ws + off);           off += (size_t)p.N * 4;
    off = (off + 15) & ~(size_t)15;
    p.energy_acc = (double*)((char*)d_ws + off);          off += 8;
    p.ce_acc     = (double*)((char*)d_ws + off);          off += 8;
    p.hitCount   = (unsigned int*)((char*)d_ws + off);    off += 16;
    p.hits       = (int2*)((char*)d_ws + off);

    p.out = (float*)d_out;

    void* args[] = { &p };
    hipLaunchCooperativeKernel((const void*)fused_gcod, dim3(512), dim3(256),
                               args, 0, stream);
}

// Round 3
// 43.084 us; speedup vs baseline: 4.7535x; 4.7535x over previous
//
#include <hip/hip_runtime.h>
#include <math.h>

// ---------------- K1: zero deg + accumulators ----------------
__global__ void k1_init(unsigned int* __restrict__ deg, int N,
                        double* __restrict__ energy_acc,
                        unsigned int* __restrict__ hitCount,
                        unsigned int* __restrict__ doneCount) {
    int tid = blockIdx.x * blockDim.x + threadIdx.x;
    int nthreads = gridDim.x * blockDim.x;
    for (int i = tid; i < N; i += nthreads) deg[i] = 0u;
    if (tid == 0) { *energy_acc = 0.0; *hitCount = 0u; *doneCount = 0u; }
}

// ---------------- K2: deg atomics + hit compaction + CE (block 0) --------
__global__ __launch_bounds__(256) void k2_deg_compact_ce(
        const int* __restrict__ row, const int* __restrict__ col,
        const int* __restrict__ batch, unsigned int* __restrict__ deg,
        unsigned int* __restrict__ hitCount, int2* __restrict__ hits, int E,
        const float* __restrict__ logits, const int* __restrict__ labels,
        double* __restrict__ ce_acc, int G, int C) {
    int e = blockIdx.x * blockDim.x + threadIdx.x;
    if (e < E) {
        int r = row[e], c = col[e];
        if (batch[r] == batch[c]) {
            atomicAdd(&deg[r], 1u);
            unsigned int idx = atomicAdd(hitCount, 1u);
            hits[idx] = make_int2(r, c);
        }
    }
    // CE on block 0 (independent work, rides along)
    if (blockIdx.x == 0) {
        __shared__ float sh[128];
        int g = threadIdx.x;
        if (g < 128) {
            float lp = 0.f;
            if (g < G) {
                const float* lg = logits + (size_t)g * C;
                float m = lg[0];
                for (int d = 1; d < C; ++d) m = fmaxf(m, lg[d]);
                float s = 0.f;
                for (int d = 0; d < C; ++d) s += expf(lg[d] - m);
                lp = lg[labels[g]] - m - logf(s);
            }
            sh[g] = lp;
        }
        __syncthreads();
        for (int o = 64; o > 0; o >>= 1) {
            if (threadIdx.x < o) sh[threadIdx.x] += sh[threadIdx.x + o];
            __syncthreads();
        }
        if (threadIdx.x == 0) *ce_acc = -(double)sh[0] / (double)G;
    }
}

// ---------------- K3: energy over hits + last-block finalize -------------
__global__ __launch_bounds__(256) void k3_energy_finalize(
        const float* __restrict__ x, const unsigned int* __restrict__ deg,
        const unsigned int* __restrict__ hitCount, const int2* __restrict__ hits,
        double* __restrict__ energy_acc, unsigned int* __restrict__ doneCount,
        const double* __restrict__ ce_acc, const int* __restrict__ batch,
        int N, int D, float* __restrict__ out) {
    const int tid = blockIdx.x * blockDim.x + threadIdx.x;
    const int lane = threadIdx.x & 63;
    const int wave = tid >> 6;
    const int nwaves = (gridDim.x * blockDim.x) >> 6;
    const int nH = (int)(*hitCount);

    double wsum = 0.0;
    for (int h = wave; h < nH; h += nwaves) {
        int2 rc = hits[h];
        unsigned int dr = deg[rc.x];
        unsigned int dc = deg[rc.y];
        if (dc == 0u) continue;  // dr >= 1 guaranteed by construction
        const float4 a = ((const float4*)(x + (size_t)rc.x * (size_t)D))[lane];
        const float4 b = ((const float4*)(x + (size_t)rc.y * (size_t)D))[lane];
        float dx = a.x - b.x, dy = a.y - b.y, dz = a.z - b.z, dw = a.w - b.w;
        float ss = dx * dx + dy * dy + dz * dz + dw * dw;
        #pragma unroll
        for (int o = 32; o > 0; o >>= 1) ss += __shfl_xor(ss, o);
        if (lane == 0) {
            float ir = 1.0f / sqrtf((float)dr);
            float ic = 1.0f / sqrtf((float)dc);
            wsum += (double)((ir * ic) * ss);
        }
    }
    if (lane == 0 && wsum != 0.0) atomicAdd(energy_acc, wsum);

    // last-block finalize
    __syncthreads();
    if (threadIdx.x == 0) {
        __threadfence();
        unsigned int done = atomicAdd(doneCount, 1u);
        if (done == gridDim.x - 1) {
            double energy = atomicAdd(energy_acc, 0.0);  // coherent read
            double ce = *ce_acc;
            double ng = (double)(batch[N - 1] + 1);
            out[0] = (float)(ce + energy / ng);
        }
    }
}

extern "C" void kernel_launch(void* const* d_in, const int* in_sizes, int n_in,
                              void* d_out, int out_size, void* d_ws, size_t ws_size,
                              hipStream_t stream) {
    const float* logits = (const float*)d_in[0];
    const int* labels = (const int*)d_in[1];
    const float* x = (const float*)d_in[2];
    const int* edge_index = (const int*)d_in[3];
    const int* batch = (const int*)d_in[4];

    const int C = 10;
    const int G = in_sizes[0] / C;   // 128
    const int E = in_sizes[3] / 2;   // 320000
    const int N = in_sizes[4];       // 100000
    const int D = in_sizes[2] / N;   // 256

    const int* row = edge_index;
    const int* col = edge_index + E;

    // workspace: deg[N] | energy_acc | ce_acc | hitCount | doneCount | hits[E]
    size_t off = 0;
    unsigned int* deg = (unsigned int*)((char*)d_ws + off); off += (size_t)N * 4;
    off = (off + 15) & ~(size_t)15;
    double* energy_acc = (double*)((char*)d_ws + off);      off += 8;
    double* ce_acc     = (double*)((char*)d_ws + off);      off += 8;
    unsigned int* hitCount  = (unsigned int*)((char*)d_ws + off); off += 4;
    unsigned int* doneCount = (unsigned int*)((char*)d_ws + off); off += 4;
    off = (off + 15) & ~(size_t)15;
    int2* hits = (int2*)((char*)d_ws + off);

    float* out = (float*)d_out;

    k1_init<<<256, 256, 0, stream>>>(deg, N, energy_acc, hitCount, doneCount);

    int k2Blocks = (E + 255) / 256;
    k2_deg_compact_ce<<<k2Blocks, 256, 0, stream>>>(
        row, col, batch, deg, hitCount, hits, E,
        logits, labels, ce_acc, G, C);

    k3_energy_finalize<<<128, 256, 0, stream>>>(
        x, deg, hitCount, hits, energy_acc, doneCount,
        ce_acc, batch, N, D, out);
}